// Round 9
// baseline (394.487 us; speedup 1.0000x reference)
//
#include <hip/hip_runtime.h>

typedef unsigned short ushort;
typedef short bf16x8 __attribute__((ext_vector_type(8)));   // 8 bf16 in 4 VGPRs
typedef float f32x4 __attribute__((ext_vector_type(4)));

static __device__ __forceinline__ ushort f2b(float f) {
  unsigned u = __builtin_bit_cast(unsigned, f);
  u = (u + 0x7fffu + ((u >> 16) & 1u)) >> 16;
  return (ushort)u;
}
static __device__ __forceinline__ float b2f(ushort b) {
  return __builtin_bit_cast(float, (unsigned)b << 16);
}

// async global->LDS, 16B per lane; LDS dest is wave-uniform base + lane*16
static __device__ __forceinline__ void gll16(const ushort* g, ushort* l) {
  __builtin_amdgcn_global_load_lds(
      (const __attribute__((address_space(1))) void*)g,
      (__attribute__((address_space(3))) void*)l, 16, 0, 0);
}

// ---------------------------------------------------------------------------
// prep: LDS-tiled 32x32 transpose for all five fp32->bf16 transposes.
// ---------------------------------------------------------------------------
__global__ __launch_bounds__(256) void prep_kernel(
    const float* __restrict__ x,
    const float* __restrict__ w_qkv, const float* __restrict__ w_proj,
    const float* __restrict__ w_fc1, const float* __restrict__ w_fc2,
    ushort* __restrict__ xb, ushort* __restrict__ wqkvT,
    ushort* __restrict__ wprojT, ushort* __restrict__ wfc1T,
    ushort* __restrict__ wfc2T)
{
  __shared__ float tile[32][33];
  int t = blockIdx.x;
  const float* src; ushort* dst; int R, Nc, r0, c0;
  if (t < 2048)              { src = x;      dst = xb;     R = 256; Nc = 8192; r0 = (t >> 8) * 32; c0 = (t & 255) * 32; }
  else if ((t -= 2048) < 192){ src = w_qkv;  dst = wqkvT;  R = 256; Nc = 768;  r0 = (t / 24) * 32; c0 = (t % 24) * 32; }
  else if ((t -= 192) < 64)  { src = w_proj; dst = wprojT; R = 256; Nc = 256;  r0 = (t / 8) * 32;  c0 = (t % 8) * 32; }
  else if ((t -= 64) < 128)  { src = w_fc1;  dst = wfc1T;  R = 256; Nc = 512;  r0 = (t / 16) * 32; c0 = (t % 16) * 32; }
  else           { t -= 128;   src = w_fc2;  dst = wfc2T;  R = 512; Nc = 256;  r0 = (t / 8) * 32;  c0 = (t % 8) * 32; }

  const int tx = threadIdx.x & 31, ty = threadIdx.x >> 5;
  #pragma unroll
  for (int i = 0; i < 4; i++)
    tile[ty + i * 8][tx] = src[(size_t)(r0 + ty + i * 8) * Nc + c0 + tx];
  __syncthreads();
  #pragma unroll
  for (int i = 0; i < 4; i++)
    dst[(size_t)(c0 + ty + i * 8) * R + r0 + tx] = f2b(tile[tx][ty + i * 8]);
}

// ---------------------------------------------------------------------------
// MFMA bf16 GEMM, 64x64 tile, 4 waves, BK=128 (v2 engine, gll16 staging).
// Used only for the qkv GEMM (EPI 0):
//   q,k rows to C0[m*N+n]; v (n>=512) -> C1 vT[(n-512)*8192+m]
// ---------------------------------------------------------------------------
template<int EPI, int KD>
__global__ __launch_bounds__(256) void gemm_mfma(
    const ushort* __restrict__ A, const ushort* __restrict__ Bt,
    const float* __restrict__ bias, const float* __restrict__ R,
    const ushort* __restrict__ RS,
    void* __restrict__ C0, void* __restrict__ C1,
    int M, int N)
{
  __shared__ __attribute__((aligned(16))) ushort As[64 * 128];
  __shared__ __attribute__((aligned(16))) ushort Bs[64 * 128];

  const int bm = blockIdx.y * 64;
  const int bn = blockIdx.x * 64;
  const int t  = threadIdx.x;
  const int w    = t >> 6;
  const int lane = t & 63;
  const int wm = (w & 1) * 32;
  const int wn = (w >> 1) * 32;
  const int lm = lane & 15;
  const int kq = lane >> 4;                     // 0..3

  const int rl  = lane >> 4;                    // row within chunk
  const int cbx = (lane & 15) << 4;             // byte col within row
  const int xr  = (lm & 7) << 4;                // read-side XOR

  f32x4 acc[2][2] = {};

  #pragma unroll
  for (int k0 = 0; k0 < KD; k0 += 128) {
    #pragma unroll
    for (int s = 0; s < 4; s++) {
      const int c = w * 4 + s;
      const int r = c * 4 + rl;                                // tile row 0..63
      const int off = (cbx ^ ((r & 7) << 4)) >> 1;             // swizzled src (ushorts)
      gll16(A  + (size_t)(bm + r) * KD + k0 + off, As + c * 512);
      gll16(Bt + (size_t)(bn + r) * KD + k0 + off, Bs + c * 512);
    }
    __syncthreads();

    #pragma unroll
    for (int ks = 0; ks < 4; ks++) {
      const int kb = ks * 64 + (kq << 4);       // byte offset within row
      const int cs = kb ^ xr;                   // swizzled read col (bytes)
      bf16x8 a0 = *(const bf16x8*)((const char*)As + (wm + lm)      * 256 + cs);
      bf16x8 a1 = *(const bf16x8*)((const char*)As + (wm + 16 + lm) * 256 + cs);
      bf16x8 b0 = *(const bf16x8*)((const char*)Bs + (wn + lm)      * 256 + cs);
      bf16x8 b1 = *(const bf16x8*)((const char*)Bs + (wn + 16 + lm) * 256 + cs);
      acc[0][0] = __builtin_amdgcn_mfma_f32_16x16x32_bf16(a0, b0, acc[0][0], 0, 0, 0);
      acc[0][1] = __builtin_amdgcn_mfma_f32_16x16x32_bf16(a0, b1, acc[0][1], 0, 0, 0);
      acc[1][0] = __builtin_amdgcn_mfma_f32_16x16x32_bf16(a1, b0, acc[1][0], 0, 0, 0);
      acc[1][1] = __builtin_amdgcn_mfma_f32_16x16x32_bf16(a1, b1, acc[1][1], 0, 0, 0);
    }
    __syncthreads();
  }

  #pragma unroll
  for (int ti = 0; ti < 2; ti++) {
    #pragma unroll
    for (int tj = 0; tj < 2; tj++) {
      const int n  = bn + wn + tj * 16 + lm;
      const int m0 = bm + wm + ti * 16 + kq * 4;
      if (EPI == 0) {
        if (n < 512) {
          #pragma unroll
          for (int r = 0; r < 4; r++)
            ((ushort*)C0)[(size_t)(m0 + r) * N + n] = f2b(acc[ti][tj][r] + bias[n]);
        } else {
          ushort4 st;
          st.x = f2b(acc[ti][tj][0] + bias[n]);
          st.y = f2b(acc[ti][tj][1] + bias[n]);
          st.z = f2b(acc[ti][tj][2] + bias[n]);
          st.w = f2b(acc[ti][tj][3] + bias[n]);
          *(ushort4*)((ushort*)C1 + (size_t)(n - 512) * 8192 + m0) = st;
        }
      }
    }
  }
}

// ---------------------------------------------------------------------------
// MFMA neighborhood attention v3 (unchanged).
// ---------------------------------------------------------------------------
__global__ __launch_bounds__(256, 4) void natt_mfma(
    const ushort* __restrict__ qkv, const ushort* __restrict__ vT,
    const float* __restrict__ rpb, ushort* __restrict__ att)
{
  __shared__ __attribute__((aligned(16))) ushort Plds[4][7][16][40];
  __shared__ float Rlds[4][176];

  const int w    = threadIdx.x >> 6;
  const int lane = threadIdx.x & 63;
  const int l  = lane & 15;
  const int q  = lane >> 4;
  const int tile = blockIdx.x;            // 0..511
  const int n    = blockIdx.y * 4 + w;    // head 0..7
  const int ph  = tile >> 3;
  const int pw0 = (tile & 7) << 4;
  const int p0  = ph * 128 + pw0;

  int sh = ph - 3;  sh = sh < 0 ? 0 : (sh > 57 ? 57 : sh);
  int sb = pw0 - 3; sb = sb < 0 ? 0 : sb;
  const int sba = sb & ~7;                // 16B-aligned span base

  const float L2E = 1.44269504f;
  for (int idx = lane; idx < 169; idx += 64)
    Rlds[w][idx] = rpb[n * 169 + idx] * L2E;

  bf16x8 qf = *(const bf16x8*)(qkv + (size_t)(p0 + l) * 768 + n * 32 + q * 8);

  const float KSC = 0.17677669529663689f * 1.44269504f;  // hd^-0.5 * log2(e)
  const int relh0 = sh - ph + 6;          // 0..6
  float rsum[4] = {0.f, 0.f, 0.f, 0.f};

  #pragma unroll
  for (int h = 0; h < 2; h++) {
    f32x4 s[7] = {};
    #pragma unroll
    for (int i = 0; i < 7; i++) {
      const int rowp = (sh + i) * 128;
      int jc = sba + h * 16 + l;
      jc = jc > 127 ? 127 : jc;           // clamp addr; junk masked below
      bf16x8 kf = *(const bf16x8*)(qkv + (size_t)(rowp + jc) * 768 + 256 + n * 32 + q * 8);
      s[i] = __builtin_amdgcn_mfma_f32_16x16x32_bf16(qf, kf, s[i], 0, 0, 0);
    }
    #pragma unroll
    for (int r = 0; r < 4; r++) {
      const int pw = pw0 + q * 4 + r;
      int sw = pw - 3; sw = sw < 0 ? 0 : (sw > 121 ? 121 : sw);
      const int jc = sba + h * 16 + l;
      const bool valid = (unsigned)(jc - sw) <= 6u;
      int relw = jc - pw + 6;
      relw = relw < 0 ? 0 : (relw > 12 ? 12 : relw);
      #pragma unroll
      for (int i = 0; i < 7; i++) {
        float b = Rlds[w][(relh0 + i) * 13 + relw];
        float v = s[i][r] * KSC + b;
        v = valid ? v : -1e30f;
        float e = exp2f(v);
        rsum[r] += e;
        Plds[w][i][q * 4 + r][h * 16 + l] = f2b(e);
      }
    }
  }

  #pragma unroll
  for (int r = 0; r < 4; r++) {
    rsum[r] += __shfl_xor(rsum[r], 1);
    rsum[r] += __shfl_xor(rsum[r], 2);
    rsum[r] += __shfl_xor(rsum[r], 4);
    rsum[r] += __shfl_xor(rsum[r], 8);
  }

  f32x4 o[2] = {};
  #pragma unroll
  for (int i = 0; i < 7; i++) {
    bf16x8 pf = *(const bf16x8*)(&Plds[w][i][l][q * 8]);
    const int rowp = (sh + i) * 128;
    #pragma unroll
    for (int dh = 0; dh < 2; dh++) {
      bf16x8 vf = *(const bf16x8*)(vT + (size_t)(n * 32 + dh * 16 + l) * 8192
                                      + rowp + sba + q * 8);
      o[dh] = __builtin_amdgcn_mfma_f32_16x16x32_bf16(pf, vf, o[dh], 0, 0, 0);
    }
  }

  #pragma unroll
  for (int r = 0; r < 4; r++) {
    const float inv = 1.0f / rsum[r];
    #pragma unroll
    for (int dh = 0; dh < 2; dh++)
      att[(size_t)(p0 + q * 4 + r) * 256 + n * 32 + dh * 16 + l] = f2b(o[dh][r] * inv);
  }
}

// ---------------------------------------------------------------------------
// Fused proj + fc1(gelu) + fc2 + both residuals, v7: small-block 2-phase.
// Same proven v4 structure (sync; stage(p+1); compute(p); __syncthreads),
// but 512 blocks x 256 threads (16 rows/block), 64-weight-row phases,
// LDS 48KB (Bs 2x16K + X1 8K + Hs 8K) -> 2 blocks/CU: two independent
// barrier groups per CU interleave (m114), hiding each other's stage drains.
// 40 phases, fully unrolled from constexpr tables (all indices static).
// ---------------------------------------------------------------------------
__global__ __launch_bounds__(256, 3) void mlp_fused(
    const ushort* __restrict__ att, const ushort* __restrict__ wprojT,
    const ushort* __restrict__ wfc1T, const ushort* __restrict__ wfc2T,
    const float* __restrict__ b_proj, const float* __restrict__ b_fc1,
    const float* __restrict__ b_fc2, const float* __restrict__ xres,
    float* __restrict__ out)
{
  __shared__ __attribute__((aligned(16))) ushort Bs[2][64 * 128];  // 32KB
  __shared__ __attribute__((aligned(16))) ushort X1[16 * 256];     // 8KB, swz
  __shared__ __attribute__((aligned(16))) ushort Hs[16 * 256];     // 8KB, swz

  const int bm   = blockIdx.x * 16;
  const int w    = threadIdx.x >> 6;     // 0..3
  const int lane = threadIdx.x & 63;
  const int lm   = lane & 15;
  const int kq   = lane >> 4;            // 0..3
  const int wnn  = w * 16;               // wave col base within 64-col phase
  const int rl   = lane >> 4;
  const int swl  = (lane & 15) << 3;

  // ---- preload A-rows (att) and all epilogue vmem into registers ----
  bf16x8 af[2][4];
  #pragma unroll
  for (int kt = 0; kt < 2; kt++)
    #pragma unroll
    for (int ks = 0; ks < 4; ks++)
      af[kt][ks] = *(const bf16x8*)(att + (size_t)(bm + lm) * 256
                                    + kt * 128 + ks * 32 + kq * 8);
  float4 xr4[4];
  float bpv[4], bf1v[2][4], bf2v[4];
  #pragma unroll
  for (int np = 0; np < 4; np++) {
    const int n = np * 64 + wnn + lm;
    xr4[np]     = *(const float4*)(xres + (size_t)n * 8192 + bm + kq * 4);
    bpv[np]     = b_proj[n];
    bf1v[0][np] = b_fc1[n];
    bf1v[1][np] = b_fc1[256 + n];
    bf2v[np]    = b_fc2[n];
  }

  // stage one 64row x 128k weight chunk into Bs[b] (4 gll16/wave, 16 chunks)
  auto stage = [&](int b, const ushort* __restrict__ src, int ldk, int row0, int col0) {
    #pragma unroll
    for (int s = 0; s < 4; s++) {
      const int c = w * 4 + s;                  // chunk 0..15
      const int n = c * 4 + rl;                 // phase-local row 0..63
      gll16(src + (size_t)(row0 + n) * ldk + col0 + (swl ^ ((n & 7) << 3)),
            &Bs[b][c * 512]);
    }
  };
  auto compP = [&](int b, int kt, f32x4& a4) {  // A from regs
    #pragma unroll
    for (int ks = 0; ks < 4; ks++) {
      const int kc = ks * 32 + kq * 8;
      const int nr = wnn + lm;
      bf16x8 bfr = *(const bf16x8*)(&Bs[b][nr * 128 + (kc ^ ((nr & 7) << 3))]);
      a4 = __builtin_amdgcn_mfma_f32_16x16x32_bf16(af[kt][ks], bfr, a4, 0, 0, 0);
    }
  };
  auto compS = [&](int b, const ushort* __restrict__ S, int kt, f32x4& a4) {
    #pragma unroll
    for (int ks = 0; ks < 4; ks++) {
      const int kc = ks * 32 + kq * 8;
      const int ac = kt * 128 + kc;
      bf16x8 a = *(const bf16x8*)(S + lm * 256 + (ac ^ ((lm & 7) << 3)));
      const int nr = wnn + lm;
      bf16x8 bfr = *(const bf16x8*)(&Bs[b][nr * 128 + (kc ^ ((nr & 7) << 3))]);
      a4 = __builtin_amdgcn_mfma_f32_16x16x32_bf16(a, bfr, a4, 0, 0, 0);
    }
  };
  auto projEpi = [&](int np, f32x4& a4) {
    const int n = np * 64 + wnn + lm;
    const float* xp = (const float*)&xr4[np];
    #pragma unroll
    for (int r = 0; r < 4; r++) {
      const int m = kq * 4 + r;
      X1[m * 256 + (n ^ ((m & 7) << 3))] = f2b(a4[r] + bpv[np] + xp[r]);
    }
  };
  auto fc1Epi = [&](int hf, int np, f32x4& a4) {
    const int n = np * 64 + wnn + lm;
    #pragma unroll
    for (int r = 0; r < 4; r++) {
      const int m = kq * 4 + r;
      float v = a4[r] + bf1v[hf][np];
      v = 0.5f * v * (1.0f + erff(v * 0.70710678118f));
      Hs[m * 256 + (n ^ ((m & 7) << 3))] = f2b(v);
    }
  };

  // phase tables: 0-7 proj, 8-15 fc1h0, 16-23 fc2h0, 24-31 fc1h1, 32-39 fc2h1
  constexpr int WHICH[40] = {0,0,0,0,0,0,0,0, 1,1,1,1,1,1,1,1, 2,2,2,2,2,2,2,2,
                             1,1,1,1,1,1,1,1, 2,2,2,2,2,2,2,2};
  constexpr int ROW0[40]  = {0,0,64,64,128,128,192,192, 0,0,64,64,128,128,192,192,
                             0,0,64,64,128,128,192,192, 256,256,320,320,384,384,448,448,
                             0,0,64,64,128,128,192,192};
  constexpr int COL0[40]  = {0,128,0,128,0,128,0,128, 0,128,0,128,0,128,0,128,
                             0,128,0,128,0,128,0,128, 0,128,0,128,0,128,0,128,
                             256,384,256,384,256,384,256,384};
  const ushort* const srcs[3] = {wprojT, wfc1T, wfc2T};
  const int ldks[3] = {256, 256, 512};

  f32x4 accp = {}, acch = {};
  f32x4 acco[4] = {};

  stage(0, srcs[WHICH[0]], ldks[WHICH[0]], ROW0[0], COL0[0]);     // p0

  #pragma unroll
  for (int p = 0; p < 40; p++) {
    const int buf = p & 1;
    __syncthreads();
    if (p < 39)
      stage(buf ^ 1, srcs[WHICH[p + 1]], ldks[WHICH[p + 1]], ROW0[p + 1], COL0[p + 1]);
    const int np = (p >> 1) & 3;
    const int kt = p & 1;
    if (WHICH[p] == 0) {
      if (kt == 0) accp = f32x4{};
      compP(buf, kt, accp);
      if (kt == 1) projEpi(np, accp);
    } else if (WHICH[p] == 1) {
      if (kt == 0) acch = f32x4{};
      compS(buf, X1, kt, acch);
      if (kt == 1) fc1Epi(p >= 24 ? 1 : 0, np, acch);
    } else {
      compS(buf, Hs, kt, acco[np]);
    }
  }

  // ---------------- fc2 epilogue: + b_fc2 + x1 residual, f32 chw -----------
  #pragma unroll
  for (int np = 0; np < 4; np++) {
    const int n = np * 64 + wnn + lm;
    float4 v;
    float* vp = &v.x;
    #pragma unroll
    for (int r = 0; r < 4; r++) {
      const int m = kq * 4 + r;
      vp[r] = acco[np][r] + bf2v[np] + b2f(X1[m * 256 + (n ^ ((m & 7) << 3))]);
    }
    *(float4*)(out + (size_t)n * 8192 + bm + kq * 4) = v;
  }
}

// ---------------------------------------------------------------------------
extern "C" void kernel_launch(void* const* d_in, const int* in_sizes, int n_in,
                              void* d_out, int out_size, void* d_ws, size_t ws_size,
                              hipStream_t stream)
{
  const float* x      = (const float*)d_in[0];
  const float* w_qkv  = (const float*)d_in[1];
  const float* b_qkv  = (const float*)d_in[2];
  const float* rpb    = (const float*)d_in[3];
  const float* w_proj = (const float*)d_in[4];
  const float* b_proj = (const float*)d_in[5];
  const float* w_fc1  = (const float*)d_in[6];
  const float* b_fc1  = (const float*)d_in[7];
  const float* w_fc2  = (const float*)d_in[8];
  const float* b_fc2  = (const float*)d_in[9];
  float* out = (float*)d_out;

  const int M = 8192;
  char* ws = (char*)d_ws;
  ushort* xb     = (ushort*)(ws);               //  4,194,304 B (reused as att)
  ushort* qkv    = (ushort*)(ws + 4194304);     // 12,582,912 B
  ushort* wqkvT  = (ushort*)(ws + 20971520);    //    393,216 B
  ushort* wprojT = (ushort*)(ws + 21364736);    //    131,072 B
  ushort* wfc1T  = (ushort*)(ws + 21495808);    //    262,144 B
  ushort* wfc2T  = (ushort*)(ws + 21757952);    //    262,144 B
  ushort* vT     = (ushort*)(ws + 22020096);    //  4,194,304 B + 64K pad
  ushort* att = xb;                             // xb dead after qkv GEMM

  dim3 blk(256);

  prep_kernel<<<dim3(2560), blk, 0, stream>>>(
      x, w_qkv, w_proj, w_fc1, w_fc2, xb, wqkvT, wprojT, wfc1T, wfc2T);

  // qkv = xb @ wqkvT^T + b_qkv  -> q,k rows + transposed vT
  gemm_mfma<0, 256><<<dim3(768 / 64, M / 64), blk, 0, stream>>>(
      xb, wqkvT, b_qkv, nullptr, nullptr, qkv, vT, M, 768);

  natt_mfma<<<dim3(512, 2), blk, 0, stream>>>(qkv, vT, rpb, att);

  // out = fc2(gelu(fc1(proj(att)+x))) + x1, one kernel, small-block 2-phase
  mlp_fused<<<dim3(512), dim3(256), 0, stream>>>(
      att, wprojT, wfc1T, wfc2T, b_proj, b_fc1, b_fc2, x, out);
}

// Round 10
// 133.193 us; speedup vs baseline: 2.9618x; 2.9618x over previous
//
#include <hip/hip_runtime.h>

typedef unsigned short ushort;
typedef short bf16x8 __attribute__((ext_vector_type(8)));   // 8 bf16 in 4 VGPRs
typedef float f32x4 __attribute__((ext_vector_type(4)));

static __device__ __forceinline__ ushort f2b(float f) {
  unsigned u = __builtin_bit_cast(unsigned, f);
  u = (u + 0x7fffu + ((u >> 16) & 1u)) >> 16;
  return (ushort)u;
}
static __device__ __forceinline__ float b2f(ushort b) {
  return __builtin_bit_cast(float, (unsigned)b << 16);
}

// async global->LDS, 16B per lane; LDS dest is wave-uniform base + lane*16
static __device__ __forceinline__ void gll16(const ushort* g, ushort* l) {
  __builtin_amdgcn_global_load_lds(
      (const __attribute__((address_space(1))) void*)g,
      (__attribute__((address_space(3))) void*)l, 16, 0, 0);
}

// ---------------------------------------------------------------------------
// prep: LDS-tiled 32x32 transpose for all five fp32->bf16 transposes.
// ---------------------------------------------------------------------------
__global__ __launch_bounds__(256) void prep_kernel(
    const float* __restrict__ x,
    const float* __restrict__ w_qkv, const float* __restrict__ w_proj,
    const float* __restrict__ w_fc1, const float* __restrict__ w_fc2,
    ushort* __restrict__ xb, ushort* __restrict__ wqkvT,
    ushort* __restrict__ wprojT, ushort* __restrict__ wfc1T,
    ushort* __restrict__ wfc2T)
{
  __shared__ float tile[32][33];
  int t = blockIdx.x;
  const float* src; ushort* dst; int R, Nc, r0, c0;
  if (t < 2048)              { src = x;      dst = xb;     R = 256; Nc = 8192; r0 = (t >> 8) * 32; c0 = (t & 255) * 32; }
  else if ((t -= 2048) < 192){ src = w_qkv;  dst = wqkvT;  R = 256; Nc = 768;  r0 = (t / 24) * 32; c0 = (t % 24) * 32; }
  else if ((t -= 192) < 64)  { src = w_proj; dst = wprojT; R = 256; Nc = 256;  r0 = (t / 8) * 32;  c0 = (t % 8) * 32; }
  else if ((t -= 64) < 128)  { src = w_fc1;  dst = wfc1T;  R = 256; Nc = 512;  r0 = (t / 16) * 32; c0 = (t % 16) * 32; }
  else           { t -= 128;   src = w_fc2;  dst = wfc2T;  R = 512; Nc = 256;  r0 = (t / 8) * 32;  c0 = (t % 8) * 32; }

  const int tx = threadIdx.x & 31, ty = threadIdx.x >> 5;
  #pragma unroll
  for (int i = 0; i < 4; i++)
    tile[ty + i * 8][tx] = src[(size_t)(r0 + ty + i * 8) * Nc + c0 + tx];
  __syncthreads();
  #pragma unroll
  for (int i = 0; i < 4; i++)
    dst[(size_t)(c0 + ty + i * 8) * R + r0 + tx] = f2b(tile[tx][ty + i * 8]);
}

// ---------------------------------------------------------------------------
// qkv GEMM, NEW 128x128-tile engine (m93->m97 ladder step: 874-912 TF vs
// ~350-400 TF for the 64^2 tile). 256 threads, 4 waves in 2x2, each wave a
// 64x64 sub-tile = 4x4 fragments. BK=64 (LDS 2x16KB), gll16 staging with
// XOR swizzle re-derived for 128B rows (chunk = 8 rows, XOR (row&7)<<4,
// fragment reads 2 lanes/bank = free). Epilogue = EPI0 (unchanged math):
// q,k rows (n<512) -> C0[m*768+n]; v -> C1 vT[(n-512)*8192+m].
// ---------------------------------------------------------------------------
__global__ __launch_bounds__(256) void gemm_qkv(
    const ushort* __restrict__ A, const ushort* __restrict__ Bt,
    const float* __restrict__ bias,
    ushort* __restrict__ C0, ushort* __restrict__ C1)
{
  __shared__ __attribute__((aligned(16))) ushort As[128 * 64];   // 16KB
  __shared__ __attribute__((aligned(16))) ushort Bs[128 * 64];   // 16KB

  const int bm = blockIdx.y * 128;
  const int bn = blockIdx.x * 128;
  const int w    = threadIdx.x >> 6;
  const int lane = threadIdx.x & 63;
  const int lm = lane & 15;
  const int kq = lane >> 4;                    // 0..3
  const int wm = (w & 1) * 64;
  const int wn = (w >> 1) * 64;

  const int rl  = lane >> 3;                   // row within 8-row chunk (0..7)
  const int cbx = (lane & 7) << 4;             // byte col within 128B row
  const int xr  = (lm & 7) << 4;               // read-side XOR

  f32x4 acc[4][4] = {};

  #pragma unroll
  for (int k0 = 0; k0 < 256; k0 += 64) {
    #pragma unroll
    for (int s = 0; s < 4; s++) {
      const int c = w * 4 + s;                                // chunk 0..15
      const int r = c * 8 + rl;                               // tile row 0..127
      const int off = (cbx ^ ((r & 7) << 4)) >> 1;            // swz src (ushorts)
      gll16(A  + (size_t)(bm + r) * 256 + k0 + off, As + c * 512);
      gll16(Bt + (size_t)(bn + r) * 256 + k0 + off, Bs + c * 512);
    }
    __syncthreads();

    #pragma unroll
    for (int ks = 0; ks < 2; ks++) {
      const int cs = (ks * 64 + (kq << 4)) ^ xr;              // byte col, swz
      bf16x8 a[4], b[4];
      #pragma unroll
      for (int i = 0; i < 4; i++) {
        a[i] = *(const bf16x8*)((const char*)As + (wm + i * 16 + lm) * 128 + cs);
        b[i] = *(const bf16x8*)((const char*)Bs + (wn + i * 16 + lm) * 128 + cs);
      }
      #pragma unroll
      for (int i = 0; i < 4; i++)
        #pragma unroll
        for (int j = 0; j < 4; j++)
          acc[i][j] = __builtin_amdgcn_mfma_f32_16x16x32_bf16(a[i], b[j], acc[i][j], 0, 0, 0);
    }
    __syncthreads();
  }

  #pragma unroll
  for (int ti = 0; ti < 4; ti++) {
    #pragma unroll
    for (int tj = 0; tj < 4; tj++) {
      const int n  = bn + wn + tj * 16 + lm;
      const int m0 = bm + wm + ti * 16 + kq * 4;
      if (n < 512) {
        #pragma unroll
        for (int r = 0; r < 4; r++)
          C0[(size_t)(m0 + r) * 768 + n] = f2b(acc[ti][tj][r] + bias[n]);
      } else {
        ushort4 st;
        st.x = f2b(acc[ti][tj][0] + bias[n]);
        st.y = f2b(acc[ti][tj][1] + bias[n]);
        st.z = f2b(acc[ti][tj][2] + bias[n]);
        st.w = f2b(acc[ti][tj][3] + bias[n]);
        *(ushort4*)(C1 + (size_t)(n - 512) * 8192 + m0) = st;
      }
    }
  }
}

// ---------------------------------------------------------------------------
// MFMA neighborhood attention v3 (unchanged).
// ---------------------------------------------------------------------------
__global__ __launch_bounds__(256, 4) void natt_mfma(
    const ushort* __restrict__ qkv, const ushort* __restrict__ vT,
    const float* __restrict__ rpb, ushort* __restrict__ att)
{
  __shared__ __attribute__((aligned(16))) ushort Plds[4][7][16][40];
  __shared__ float Rlds[4][176];

  const int w    = threadIdx.x >> 6;
  const int lane = threadIdx.x & 63;
  const int l  = lane & 15;
  const int q  = lane >> 4;
  const int tile = blockIdx.x;            // 0..511
  const int n    = blockIdx.y * 4 + w;    // head 0..7
  const int ph  = tile >> 3;
  const int pw0 = (tile & 7) << 4;
  const int p0  = ph * 128 + pw0;

  int sh = ph - 3;  sh = sh < 0 ? 0 : (sh > 57 ? 57 : sh);
  int sb = pw0 - 3; sb = sb < 0 ? 0 : sb;
  const int sba = sb & ~7;                // 16B-aligned span base

  const float L2E = 1.44269504f;
  for (int idx = lane; idx < 169; idx += 64)
    Rlds[w][idx] = rpb[n * 169 + idx] * L2E;

  bf16x8 qf = *(const bf16x8*)(qkv + (size_t)(p0 + l) * 768 + n * 32 + q * 8);

  const float KSC = 0.17677669529663689f * 1.44269504f;  // hd^-0.5 * log2(e)
  const int relh0 = sh - ph + 6;          // 0..6
  float rsum[4] = {0.f, 0.f, 0.f, 0.f};

  #pragma unroll
  for (int h = 0; h < 2; h++) {
    f32x4 s[7] = {};
    #pragma unroll
    for (int i = 0; i < 7; i++) {
      const int rowp = (sh + i) * 128;
      int jc = sba + h * 16 + l;
      jc = jc > 127 ? 127 : jc;           // clamp addr; junk masked below
      bf16x8 kf = *(const bf16x8*)(qkv + (size_t)(rowp + jc) * 768 + 256 + n * 32 + q * 8);
      s[i] = __builtin_amdgcn_mfma_f32_16x16x32_bf16(qf, kf, s[i], 0, 0, 0);
    }
    #pragma unroll
    for (int r = 0; r < 4; r++) {
      const int pw = pw0 + q * 4 + r;
      int sw = pw - 3; sw = sw < 0 ? 0 : (sw > 121 ? 121 : sw);
      const int jc = sba + h * 16 + l;
      const bool valid = (unsigned)(jc - sw) <= 6u;
      int relw = jc - pw + 6;
      relw = relw < 0 ? 0 : (relw > 12 ? 12 : relw);
      #pragma unroll
      for (int i = 0; i < 7; i++) {
        float b = Rlds[w][(relh0 + i) * 13 + relw];
        float v = s[i][r] * KSC + b;
        v = valid ? v : -1e30f;
        float e = exp2f(v);
        rsum[r] += e;
        Plds[w][i][q * 4 + r][h * 16 + l] = f2b(e);
      }
    }
  }

  #pragma unroll
  for (int r = 0; r < 4; r++) {
    rsum[r] += __shfl_xor(rsum[r], 1);
    rsum[r] += __shfl_xor(rsum[r], 2);
    rsum[r] += __shfl_xor(rsum[r], 4);
    rsum[r] += __shfl_xor(rsum[r], 8);
  }

  f32x4 o[2] = {};
  #pragma unroll
  for (int i = 0; i < 7; i++) {
    bf16x8 pf = *(const bf16x8*)(&Plds[w][i][l][q * 8]);
    const int rowp = (sh + i) * 128;
    #pragma unroll
    for (int dh = 0; dh < 2; dh++) {
      bf16x8 vf = *(const bf16x8*)(vT + (size_t)(n * 32 + dh * 16 + l) * 8192
                                      + rowp + sba + q * 8);
      o[dh] = __builtin_amdgcn_mfma_f32_16x16x32_bf16(pf, vf, o[dh], 0, 0, 0);
    }
  }

  #pragma unroll
  for (int r = 0; r < 4; r++) {
    const float inv = 1.0f / rsum[r];
    #pragma unroll
    for (int dh = 0; dh < 2; dh++)
      att[(size_t)(p0 + q * 4 + r) * 256 + n * 32 + dh * 16 + l] = f2b(o[dh][r] * inv);
  }
}

// ---------------------------------------------------------------------------
// Fused proj + fc1(gelu) + fc2 + both residuals (round-1 v1, best measured
// total 132.68). 256 blocks x 512 threads, 32 rows/block; x1/h LDS-resident.
// LDS: As 8K + Bs 64K + X1 16K + Hs 16K = 104KB.
// ---------------------------------------------------------------------------
__global__ __launch_bounds__(512) void mlp_fused(
    const ushort* __restrict__ att, const ushort* __restrict__ wprojT,
    const ushort* __restrict__ wfc1T, const ushort* __restrict__ wfc2T,
    const float* __restrict__ b_proj, const float* __restrict__ b_fc1,
    const float* __restrict__ b_fc2, const float* __restrict__ xres,
    float* __restrict__ out)
{
  __shared__ __attribute__((aligned(16))) ushort As[32 * 128];    //  8KB
  __shared__ __attribute__((aligned(16))) ushort Bs[256 * 128];   // 64KB
  __shared__ __attribute__((aligned(16))) ushort X1[32 * 256];    // 16KB
  __shared__ __attribute__((aligned(16))) ushort Hs[32 * 256];    // 16KB

  const int bm   = blockIdx.x * 32;
  const int t    = threadIdx.x;
  const int w    = t >> 6;
  const int lane = t & 63;
  const int lm   = lane & 15;
  const int kq   = lane >> 4;          // 0..3
  const int wm   = (w & 1) * 16;       // wave m-offset (0/16)
  const int wn   = (w >> 1) * 64;      // wave n-offset (0/64/128/192)

  const int rl  = lane >> 4;
  const int swl = (lane & 15) << 3;

  f32x4 acc_o[4] = {};                 // fc2 accumulator, persists all phases

  // ---------------- proj: x1 = att @ wprojT^T + b_proj + x(chw) ------------
  {
    f32x4 acc_p[4] = {};
    #pragma unroll
    for (int kt = 0; kt < 2; kt++) {
      {
        const int m = w * 4 + rl;                         // As: 8 chunks
        gll16(att + (size_t)(bm + m) * 256 + kt * 128 + (swl ^ ((m & 7) << 3)),
              As + w * 512);
      }
      #pragma unroll
      for (int s = 0; s < 8; s++) {                       // Bs: 64 chunks
        const int c = w * 8 + s;
        const int n = c * 4 + rl;
        gll16(wprojT + (size_t)n * 256 + kt * 128 + (swl ^ ((n & 7) << 3)),
              Bs + c * 512);
      }
      __syncthreads();
      #pragma unroll
      for (int ks = 0; ks < 4; ks++) {
        const int kc = ks * 32 + kq * 8;
        const int ar = wm + lm;
        bf16x8 a = *(const bf16x8*)(&As[ar * 128 + (kc ^ ((ar & 7) << 3))]);
        #pragma unroll
        for (int tj = 0; tj < 4; tj++) {
          const int n = wn + tj * 16 + lm;
          bf16x8 b = *(const bf16x8*)(&Bs[n * 128 + (kc ^ ((n & 7) << 3))]);
          acc_p[tj] = __builtin_amdgcn_mfma_f32_16x16x32_bf16(a, b, acc_p[tj], 0, 0, 0);
        }
      }
      __syncthreads();
    }
    #pragma unroll
    for (int tj = 0; tj < 4; tj++) {
      const int n = wn + tj * 16 + lm;
      #pragma unroll
      for (int r = 0; r < 4; r++) {
        const int m = wm + kq * 4 + r;
        float v = acc_p[tj][r] + b_proj[n] + xres[(size_t)n * 8192 + bm + m];
        X1[m * 256 + n] = f2b(v);
      }
    }
    __syncthreads();
  }

  // ------------- fc1 (gelu) + fc2 partial, two 256-col halves --------------
  #pragma unroll
  for (int hf = 0; hf < 2; hf++) {
    f32x4 acc_h[4] = {};
    #pragma unroll
    for (int kt = 0; kt < 2; kt++) {
      #pragma unroll
      for (int s = 0; s < 8; s++) {
        const int c = w * 8 + s;
        const int n = c * 4 + rl;
        gll16(wfc1T + (size_t)(hf * 256 + n) * 256 + kt * 128 + (swl ^ ((n & 7) << 3)),
              Bs + c * 512);
      }
      __syncthreads();
      #pragma unroll
      for (int ks = 0; ks < 4; ks++) {
        const int kc = ks * 32 + kq * 8;
        const int ar = wm + lm;
        bf16x8 a = *(const bf16x8*)(&X1[ar * 256 + kt * 128 + kc]);
        #pragma unroll
        for (int tj = 0; tj < 4; tj++) {
          const int n = wn + tj * 16 + lm;
          bf16x8 b = *(const bf16x8*)(&Bs[n * 128 + (kc ^ ((n & 7) << 3))]);
          acc_h[tj] = __builtin_amdgcn_mfma_f32_16x16x32_bf16(a, b, acc_h[tj], 0, 0, 0);
        }
      }
      __syncthreads();
    }
    #pragma unroll
    for (int tj = 0; tj < 4; tj++) {
      const int n = wn + tj * 16 + lm;
      #pragma unroll
      for (int r = 0; r < 4; r++) {
        const int m = wm + kq * 4 + r;
        float v = acc_h[tj][r] + b_fc1[hf * 256 + n];
        v = 0.5f * v * (1.0f + erff(v * 0.70710678118f));
        Hs[m * 256 + n] = f2b(v);
      }
    }
    __syncthreads();

    #pragma unroll
    for (int kt = 0; kt < 2; kt++) {
      #pragma unroll
      for (int s = 0; s < 8; s++) {
        const int c = w * 8 + s;
        const int n = c * 4 + rl;
        gll16(wfc2T + (size_t)n * 512 + hf * 256 + kt * 128 + (swl ^ ((n & 7) << 3)),
              Bs + c * 512);
      }
      __syncthreads();
      #pragma unroll
      for (int ks = 0; ks < 4; ks++) {
        const int kc = ks * 32 + kq * 8;
        const int ar = wm + lm;
        bf16x8 a = *(const bf16x8*)(&Hs[ar * 256 + kt * 128 + kc]);
        #pragma unroll
        for (int tj = 0; tj < 4; tj++) {
          const int n = wn + tj * 16 + lm;
          bf16x8 b = *(const bf16x8*)(&Bs[n * 128 + (kc ^ ((n & 7) << 3))]);
          acc_o[tj] = __builtin_amdgcn_mfma_f32_16x16x32_bf16(a, b, acc_o[tj], 0, 0, 0);
        }
      }
      __syncthreads();
    }
  }

  // ---------------- fc2 epilogue: + b_fc2 + x1 residual, f32 chw -----------
  #pragma unroll
  for (int tj = 0; tj < 4; tj++) {
    const int n  = wn + tj * 16 + lm;
    const int m0 = wm + kq * 4;
    float4 v;
    float* vp = &v.x;
    #pragma unroll
    for (int r = 0; r < 4; r++)
      vp[r] = acc_o[tj][r] + b_fc2[n] + b2f(X1[(m0 + r) * 256 + n]);
    *(float4*)(out + (size_t)n * 8192 + bm + m0) = v;
  }
}

// ---------------------------------------------------------------------------
extern "C" void kernel_launch(void* const* d_in, const int* in_sizes, int n_in,
                              void* d_out, int out_size, void* d_ws, size_t ws_size,
                              hipStream_t stream)
{
  const float* x      = (const float*)d_in[0];
  const float* w_qkv  = (const float*)d_in[1];
  const float* b_qkv  = (const float*)d_in[2];
  const float* rpb    = (const float*)d_in[3];
  const float* w_proj = (const float*)d_in[4];
  const float* b_proj = (const float*)d_in[5];
  const float* w_fc1  = (const float*)d_in[6];
  const float* b_fc1  = (const float*)d_in[7];
  const float* w_fc2  = (const float*)d_in[8];
  const float* b_fc2  = (const float*)d_in[9];
  float* out = (float*)d_out;

  const int M = 8192;
  char* ws = (char*)d_ws;
  ushort* xb     = (ushort*)(ws);               //  4,194,304 B (reused as att)
  ushort* qkv    = (ushort*)(ws + 4194304);     // 12,582,912 B
  ushort* wqkvT  = (ushort*)(ws + 20971520);    //    393,216 B
  ushort* wprojT = (ushort*)(ws + 21364736);    //    131,072 B
  ushort* wfc1T  = (ushort*)(ws + 21495808);    //    262,144 B
  ushort* wfc2T  = (ushort*)(ws + 21757952);    //    262,144 B
  ushort* vT     = (ushort*)(ws + 22020096);    //  4,194,304 B + 64K pad
  ushort* att = xb;                             // xb dead after qkv GEMM

  dim3 blk(256);

  prep_kernel<<<dim3(2560), blk, 0, stream>>>(
      x, w_qkv, w_proj, w_fc1, w_fc2, xb, wqkvT, wprojT, wfc1T, wfc2T);

  // qkv = xb @ wqkvT^T + b_qkv  -> q,k rows + transposed vT (128^2 engine)
  gemm_qkv<<<dim3(768 / 128, M / 128), blk, 0, stream>>>(
      xb, wqkvT, b_qkv, qkv, vT);

  natt_mfma<<<dim3(512, 2), blk, 0, stream>>>(qkv, vT, rpb, att);

  // out = fc2(gelu(fc1(proj(att)+x))) + x1, all in one kernel (v1)
  mlp_fused<<<dim3(256), dim3(512), 0, stream>>>(
      att, wprojT, wfc1T, wfc2T, b_proj, b_fc1, b_fc2, x, out);
}